// Round 12
// baseline (674.597 us; speedup 1.0000x reference)
//
#include <hip/hip_runtime.h>
#include <hip/hip_bf16.h>

// GCN encoder: z = relu(A @ relu(A @ (x@W1) + b1) @ W2 + b2)
// R17: column-chunked XCD-pinned SpMMs. R16 exposed spmm256: 70us, FETCH
// 178MB @ 2.78 TB/s -> the 25.6MB gather table misses the 4MB per-XCD L2
// (16% capacity) and 84% of the 800K x 512B random gathers fall to L3.
// Fix: 8 column chunks; chunk = bid & 7 pins each chunk to one XCD
// (round-robin dispatch, m157 basis); sub-table 3.2MB (256-col) / 1.6MB
// (128-col) fits L2 -> gathers become L2 hits. ep re-streamed 8x (51MB,
// cheap). Wave = 1 row; lanes = (col, edge-parity); shfl_xor combine.
// gemm2 un-fused (fusion was neutral; chunking needs it separate), restored
// to the R14-verified full-B-in-LDS form. gemm1 = R15 unchanged.

typedef __attribute__((ext_vector_type(8))) short bf16x8;
typedef __attribute__((ext_vector_type(4))) float f32x4;

#define NN 50000
#define NE 800000
#define NF 512
#define NH 256
#define NL 128
#define NB ((NN + 255) / 256)

static __device__ __forceinline__ unsigned short f2bf(float f) {
  union { float f; unsigned int u; } v; v.f = f;
  unsigned int r = v.u + 0x7fffu + ((v.u >> 16) & 1u);   // RNE
  return (unsigned short)(r >> 16);
}
static __device__ __forceinline__ float bf2f(unsigned short u) {
  union { unsigned int u; float f; } v; v.u = (unsigned int)u << 16;
  return v.f;
}

// HW packed f32->bf16 (RNE), 2 elems / instruction (no builtin on gfx950).
static __device__ __forceinline__ unsigned int pkbf(float lo, float hi) {
  unsigned int r;
  asm("v_cvt_pk_bf16_f32 %0, %1, %2" : "=v"(r) : "v"(lo), "v"(hi));
  return r;
}
static __device__ __forceinline__ uint4 pk8(float4 a, float4 b) {
  uint4 o;
  o.x = pkbf(a.x, a.y); o.y = pkbf(a.z, a.w);
  o.z = pkbf(b.x, b.y); o.w = pkbf(b.z, b.w);
  return o;
}

// async global->LDS, 16B/lane; LDS dest must be wave-uniform base + lane*16.
static __device__ __forceinline__ void gll16(const void* g, void* l) {
  __builtin_amdgcn_global_load_lds(
      (const __attribute__((address_space(1))) void*)g,
      (__attribute__((address_space(3))) void*)l, 16, 0, 0);
}

// ---------------- CSR build ----------------
extern "C" __global__ void k_hist(const int* __restrict__ rows, int* __restrict__ counts, int n) {
  int i = blockIdx.x * 256 + threadIdx.x;
  if (i < n) atomicAdd(&counts[rows[i]], 1);
}

extern "C" __global__ __launch_bounds__(256) void k_blocksum(
    const int* __restrict__ counts, int* __restrict__ bsum, int n) {
  __shared__ int s[256];
  int t = threadIdx.x;
  int i = blockIdx.x * 256 + t;
  s[t] = (i < n) ? counts[i] : 0;
  __syncthreads();
  for (int off = 128; off > 0; off >>= 1) {
    if (t < off) s[t] += s[t + off];
    __syncthreads();
  }
  if (t == 0) bsum[blockIdx.x] = s[0];
}

extern "C" __global__ __launch_bounds__(256) void k_scansums(
    const int* __restrict__ bsum, int* __restrict__ bpre, int* __restrict__ rp, int nb, int n) {
  __shared__ int s[256];
  int t = threadIdx.x;
  int v = (t < nb) ? bsum[t] : 0;
  s[t] = v;
  __syncthreads();
  for (int off = 1; off < 256; off <<= 1) {
    int u = (t >= off) ? s[t - off] : 0;
    __syncthreads();
    s[t] += u;
    __syncthreads();
  }
  if (t < nb) bpre[t] = s[t] - v;
  if (t == 255) rp[n] = s[255];
}

extern "C" __global__ __launch_bounds__(256) void k_scanfin(
    const int* __restrict__ counts, const int* __restrict__ bpre,
    int* __restrict__ rp, int* __restrict__ cur, int n) {
  __shared__ int s[256];
  int t = threadIdx.x;
  int i = blockIdx.x * 256 + t;
  int c = (i < n) ? counts[i] : 0;
  s[t] = c;
  __syncthreads();
  for (int off = 1; off < 256; off <<= 1) {
    int u = (t >= off) ? s[t - off] : 0;
    __syncthreads();
    s[t] += u;
    __syncthreads();
  }
  if (i < n) {
    int e = bpre[blockIdx.x] + s[t] - c;
    rp[i] = e;
    cur[i] = e;
  }
}

extern "C" __global__ void k_scatter(const int* __restrict__ rows, const int* __restrict__ cols,
    const float* __restrict__ vals, int* __restrict__ cur, int2* __restrict__ ep, int n) {
  int i = blockIdx.x * 256 + threadIdx.x;
  if (i < n) {
    int p = atomicAdd(&cur[rows[i]], 1);
    int2 e; e.x = cols[i]; e.y = __float_as_int(vals[i]);
    ep[p] = e;
  }
}

// ---------------- merged weight transpose-cast: W1 and W2 in one launch ----------------
extern "C" __global__ void k_transcast2(const float* __restrict__ W1, unsigned short* __restrict__ w1t,
                                        const float* __restrict__ W2, unsigned short* __restrict__ w2t) {
  int b = blockIdx.x, n = threadIdx.x;
  if (b < NF) {
    w1t[(size_t)n * NF + b] = f2bf(W1[(size_t)b * NH + n]);
  } else {
    int k = b - NF;   // [0, NH)
    if (n < NL) w2t[(size_t)n * NH + k] = f2bf(W2[(size_t)k * NL + n]);
  }
}

// ---------------- GEMM1 (R15, unchanged): C[NN][256] = x * W1T^T, bf16 out ----------------
extern "C" __global__ __launch_bounds__(256, 2) void k_gemm1(
    const float* __restrict__ A, const unsigned short* __restrict__ BT,
    unsigned short* __restrict__ C) {
  __shared__ __align__(16) unsigned short sB[2][32 * 512];   // 2 x 32KB: [col][K]
  int tid = threadIdx.x;
  int lane = tid & 63, wid = tid >> 6;
  int l15 = lane & 15, lq = lane >> 4;
  int bm = blockIdx.x * 64;

  auto issueB = [&](int q, int b) {
#pragma unroll
    for (int j = 0; j < 8; ++j) {
      int u = tid + 256 * j;
      int c = u >> 6, cu = u & 63;
      int g = cu ^ (c & 7);
      gll16(BT + (size_t)(q * 32 + c) * NF + g * 8, &sB[b][u * 8]);
    }
  };

  int arow = bm + wid * 16 + l15; if (arow >= NN) arow = NN - 1;
  const float* ap = A + (size_t)arow * NF + lq * 8;

  issueB(0, 0);
  float4 apf[4][2];
#pragma unroll
  for (int p = 0; p < 4; ++p) {
    apf[p][0] = *(const float4*)(ap + p * 32);
    apf[p][1] = *(const float4*)(ap + p * 32 + 4);
  }
  __syncthreads();          // B0 resident
  issueB(1, 1);

  bf16x8 abf[16];
  f32x4 acc[16];
#pragma unroll
  for (int i = 0; i < 16; ++i) acc[i] = (f32x4){0.f, 0.f, 0.f, 0.f};

#pragma unroll
  for (int p = 0; p < 16; ++p) {
    bf16x8 bfr[2];
#pragma unroll
    for (int nt = 0; nt < 2; ++nt) {
      int c = nt * 16 + l15;
      int u = (p * 4 + lq) ^ (c & 7);
      bfr[nt] = *(const bf16x8*)(&sB[0][c * 512 + u * 8]);
    }
    union { uint4 u; bf16x8 v; } cv;
    cv.u = pk8(apf[p & 3][0], apf[p & 3][1]);
    abf[p] = cv.v;
    if (p < 12) {
      apf[p & 3][0] = *(const float4*)(ap + (p + 4) * 32);
      apf[p & 3][1] = *(const float4*)(ap + (p + 4) * 32 + 4);
    }
#pragma unroll
    for (int nt = 0; nt < 2; ++nt)
      acc[nt] = __builtin_amdgcn_mfma_f32_16x16x32_bf16(abf[p], bfr[nt], acc[nt], 0, 0, 0);
  }
  __syncthreads();

#pragma unroll
  for (int q = 1; q < 8; ++q) {
    if (q < 7) issueB(q + 1, (q + 1) & 1);
#pragma unroll
    for (int p = 0; p < 16; ++p) {
      bf16x8 bfr[2];
#pragma unroll
      for (int nt = 0; nt < 2; ++nt) {
        int c = nt * 16 + l15;
        int u = (p * 4 + lq) ^ (c & 7);
        bfr[nt] = *(const bf16x8*)(&sB[q & 1][c * 512 + u * 8]);
      }
#pragma unroll
      for (int nt = 0; nt < 2; ++nt)
        acc[q * 2 + nt] = __builtin_amdgcn_mfma_f32_16x16x32_bf16(abf[p], bfr[nt], acc[q * 2 + nt], 0, 0, 0);
    }
    if (q < 7) __syncthreads();
  }

#pragma unroll
  for (int t = 0; t < 16; ++t) {
#pragma unroll
    for (int r = 0; r < 4; ++r) {
      int gr = bm + wid * 16 + lq * 4 + r;
      if (gr < NN) {
        int gc = t * 16 + l15;
        C[(size_t)gr * NH + gc] = f2bf(acc[t][r]);
      }
    }
  }
}

// ---------------- GEMM2 (R14-verified): C[NN][128] = h[NN][256](bf16) * W2T^T ----------------
extern "C" __global__ __launch_bounds__(256, 2) void k_gemm2(
    const unsigned short* __restrict__ Ah, const unsigned short* __restrict__ BT,
    unsigned short* __restrict__ C) {
  __shared__ __align__(16) unsigned short sB[128 * 256];   // 64KB: [col][K]
  int tid = threadIdx.x;
  int lane = tid & 63, wid = tid >> 6;
  int l15 = lane & 15, lq = lane >> 4;
  int bm = blockIdx.x * 64;

#pragma unroll
  for (int j = 0; j < 16; ++j) {
    int u = tid + 256 * j;
    int row = u >> 5, cu = u & 31;
    int g = cu ^ (row & 7);
    gll16(BT + (size_t)row * NH + g * 8, &sB[u * 8]);
  }

  int arow = bm + wid * 16 + l15; if (arow >= NN) arow = NN - 1;
  const unsigned short* ap = Ah + (size_t)arow * NH + lq * 8;

  bf16x8 apf[4];
#pragma unroll
  for (int p = 0; p < 4; ++p) apf[p] = *(const bf16x8*)(ap + p * 32);

  __syncthreads();   // B resident. LAST barrier.

  f32x4 acc[8];
#pragma unroll
  for (int i = 0; i < 8; ++i) acc[i] = (f32x4){0.f, 0.f, 0.f, 0.f};

#pragma unroll
  for (int p = 0; p < 8; ++p) {
    bf16x8 bfr[8];
#pragma unroll
    for (int nt = 0; nt < 8; ++nt) {
      int c = nt * 16 + l15;
      int u = (p * 4 + lq) ^ (c & 7);
      bfr[nt] = *(const bf16x8*)(&sB[c * 256 + u * 8]);
    }
    bf16x8 af = apf[p & 3];
    if (p < 4) apf[p & 3] = *(const bf16x8*)(ap + (p + 4) * 32);
#pragma unroll
    for (int nt = 0; nt < 8; ++nt)
      acc[nt] = __builtin_amdgcn_mfma_f32_16x16x32_bf16(af, bfr[nt], acc[nt], 0, 0, 0);
  }

#pragma unroll
  for (int nt = 0; nt < 8; ++nt) {
#pragma unroll
    for (int r = 0; r < 4; ++r) {
      int gr = bm + wid * 16 + lq * 4 + r;
      if (gr < NN) {
        int gc = nt * 16 + l15;
        C[(size_t)gr * NL + gc] = f2bf(acc[nt][r]);
      }
    }
  }
}

// ---------------- SpMM 256-col, column-chunked (8 x 32 cols), XCD-pinned ----------------
// grid = 8 * NN/4; chunk = bid & 7 -> one XCD per chunk (round-robin dispatch).
// Wave = 1 row; lane: col = lane&31, eoff = lane>>5 (2 edges/iter).
extern "C" __global__ __launch_bounds__(256) void k_spmm256c(
    const int* __restrict__ rp, const int2* __restrict__ ep,
    const unsigned short* __restrict__ src, const float* __restrict__ bias,
    unsigned short* __restrict__ out) {
  int bid = blockIdx.x;
  int chunk = bid & 7;
  int row = (bid >> 3) * 4 + (threadIdx.x >> 6);
  int lane = threadIdx.x & 63;
  int col = lane & 31, eoff = lane >> 5;
  int cbase = chunk * 32;
  int e0 = __builtin_amdgcn_readfirstlane(rp[row]);
  int e1 = __builtin_amdgcn_readfirstlane(rp[row + 1]);
  const unsigned short* sc = src + cbase + col;
  float acc = 0.f;
  int e = e0;
  for (; e + 16 <= e1; e += 16) {
    int2 p[8]; unsigned short g[8];
#pragma unroll
    for (int j = 0; j < 8; ++j) p[j] = ep[e + j * 2 + eoff];
#pragma unroll
    for (int j = 0; j < 8; ++j) g[j] = sc[(size_t)p[j].x * NH];
#pragma unroll
    for (int j = 0; j < 8; ++j)
      acc = fmaf(__int_as_float(p[j].y), bf2f(g[j]), acc);
  }
  for (; e + 2 <= e1; e += 2) {
    int2 p = ep[e + eoff];
    acc = fmaf(__int_as_float(p.y), bf2f(sc[(size_t)p.x * NH]), acc);
  }
  if (e < e1 && eoff == 0) {
    int2 p = ep[e];
    acc = fmaf(__int_as_float(p.y), bf2f(sc[(size_t)p.x * NH]), acc);
  }
  acc += __shfl_xor(acc, 32);
  if (eoff == 0) {
    float v = fmaxf(acc + bias[cbase + col], 0.f);
    out[(size_t)row * NH + cbase + col] = f2bf(v);
  }
}

// ---------------- SpMM 128-col, column-chunked (8 x 16 cols), XCD-pinned ----------------
// Wave = 1 row; lane: col = lane&15, eoff = lane>>4 (4 edges/iter). fp32 out.
extern "C" __global__ __launch_bounds__(256) void k_spmm128c(
    const int* __restrict__ rp, const int2* __restrict__ ep,
    const unsigned short* __restrict__ src, const float* __restrict__ bias,
    float* __restrict__ out) {
  int bid = blockIdx.x;
  int chunk = bid & 7;
  int row = (bid >> 3) * 4 + (threadIdx.x >> 6);
  int lane = threadIdx.x & 63;
  int col = lane & 15, eoff = lane >> 4;   // 0..3
  int cbase = chunk * 16;
  int e0 = __builtin_amdgcn_readfirstlane(rp[row]);
  int e1 = __builtin_amdgcn_readfirstlane(rp[row + 1]);
  const unsigned short* sc = src + cbase + col;
  float acc = 0.f;
  int e = e0;
  for (; e + 16 <= e1; e += 16) {
    int2 p[4]; unsigned short g[4];
#pragma unroll
    for (int j = 0; j < 4; ++j) p[j] = ep[e + j * 4 + eoff];
#pragma unroll
    for (int j = 0; j < 4; ++j) g[j] = sc[(size_t)p[j].x * NL];
#pragma unroll
    for (int j = 0; j < 4; ++j)
      acc = fmaf(__int_as_float(p[j].y), bf2f(g[j]), acc);
  }
  for (; e + 4 <= e1; e += 4) {
    int2 p = ep[e + eoff];
    acc = fmaf(__int_as_float(p.y), bf2f(sc[(size_t)p.x * NL]), acc);
  }
  int r = e1 - e;   // 0..3
  if (eoff < r) {
    int2 p = ep[e + eoff];
    acc = fmaf(__int_as_float(p.y), bf2f(sc[(size_t)p.x * NL]), acc);
  }
  acc += __shfl_xor(acc, 16);
  acc += __shfl_xor(acc, 32);
  if (eoff == 0) {
    out[(size_t)row * NL + cbase + col] = fmaxf(acc + bias[cbase + col], 0.f);
  }
}

// ---------------- launch ----------------
extern "C" void kernel_launch(void* const* d_in, const int* in_sizes, int n_in,
                              void* d_out, int out_size, void* d_ws, size_t ws_size,
                              hipStream_t stream) {
  const float* x   = (const float*)d_in[0];
  const int* erow  = (const int*)d_in[1];
  const int* ecol  = (const int*)d_in[2];
  const float* ev  = (const float*)d_in[3];
  const float* W1  = (const float*)d_in[4];
  const float* b1  = (const float*)d_in[5];
  const float* W2  = (const float*)d_in[6];
  const float* b2  = (const float*)d_in[7];

  char* ws = (char*)d_ws;
  unsigned short* xwb = (unsigned short*)(ws + 0);           // 25,600,000 (x@W1 bf16)
  unsigned short* hbf = (unsigned short*)(ws + 25600000);    // 25,600,000 (h bf16)
  unsigned short* hwb = (unsigned short*)(ws + 51200000);    // 12,800,000 (h@W2 bf16)
  unsigned short* w1t = (unsigned short*)(ws + 64000000);    // 262,144
  unsigned short* w2t = (unsigned short*)(ws + 64262144);    // 65,536
  int* rp    = (int*)(ws + 64327680);                        // 200,704
  int* cur   = (int*)(ws + 64528384);                        // 200,704
  int* cnt   = (int*)(ws + 64729088);                        // 200,704
  int* bsum  = (int*)(ws + 64929792);                        // 1,024
  int* bpre  = (int*)(ws + 64930816);                        // 1,024
  int2* ep   = (int2*)(ws + 64931840);                       // 6,400,000

  // CSR build
  hipMemsetAsync(cnt, 0, NN * sizeof(int), stream);
  k_hist<<<NE / 256, 256, 0, stream>>>(erow, cnt, NE);
  k_blocksum<<<NB, 256, 0, stream>>>(cnt, bsum, NN);
  k_scansums<<<1, 256, 0, stream>>>(bsum, bpre, rp, NB, NN);
  k_scanfin<<<NB, 256, 0, stream>>>(cnt, bpre, rp, cur, NN);
  k_scatter<<<NE / 256, 256, 0, stream>>>(erow, ecol, ev, cur, ep, NE);

  // weights (merged)
  k_transcast2<<<NF + NH, NH, 0, stream>>>(W1, w1t, W2, w2t);

  // layer 1
  k_gemm1<<<(NN + 63) / 64, 256, 0, stream>>>(x, w1t, xwb);
  k_spmm256c<<<8 * (NN / 4), 256, 0, stream>>>(rp, ep, xwb, b1, hbf);

  // layer 2
  k_gemm2<<<(NN + 63) / 64, 256, 0, stream>>>(hbf, w2t, hwb);
  k_spmm128c<<<8 * (NN / 4), 256, 0, stream>>>(rp, ep, hwb, b2, (float*)d_out);
}